// Round 1
// baseline (1633.050 us; speedup 1.0000x reference)
//
#include <hip/hip_runtime.h>

// Wave-per-row, lane-per-column argmax-onehot kernel.
// lane j owns W[:, j] in 64 VGPRs; x row is read via wave-uniform scalar loads
// (SGPRs); dot is a sequential-k fmaf chain (matches BLAS accumulation order);
// argmax via DPP max-reduce + ballot/ctz (first-index tie-break like numpy).

#define DPP_MAX_STEP(v, ctrl)                                                   \
    do {                                                                        \
        int _t = __builtin_amdgcn_update_dpp(                                   \
            __float_as_int(v), __float_as_int(v), (ctrl), 0xf, 0xf, false);     \
        (v) = fmaxf((v), __int_as_float(_t));                                   \
    } while (0)

__global__ __launch_bounds__(256) void onehot_argmax_kernel(
    const float* __restrict__ x, const float* __restrict__ W,
    const float* __restrict__ b, float* __restrict__ out, int nrows)
{
    const int lane = threadIdx.x & 63;
    // readfirstlane makes the wave id provably uniform -> x row loads become s_load
    const int waveInBlock = __builtin_amdgcn_readfirstlane(threadIdx.x >> 6);
    const int wavesPerBlock = blockDim.x >> 6;
    const int gwave = blockIdx.x * wavesPerBlock + waveInBlock;
    const int nwaves = gridDim.x * wavesPerBlock;

    // lane j holds column j of W (coalesced across lanes for each k)
    float wcol[64];
#pragma unroll
    for (int k = 0; k < 64; ++k) wcol[k] = W[k * 64 + lane];
    const float bj = b[lane];

    for (int r = gwave; r < nrows; r += nwaves) {
        const float* xr = x + (size_t)r * 64u;  // wave-uniform address
        float acc = 0.0f;
#pragma unroll
        for (int k = 0; k < 64; ++k) acc = fmaf(xr[k], wcol[k], acc);
        acc += bj;  // single rounding, matches numpy's (x@W) + b

        // wave64 max via DPP: inclusive scan in 16-lane rows, then row bcasts.
        float m = acc;
        DPP_MAX_STEP(m, 0x111);  // row_shr:1
        DPP_MAX_STEP(m, 0x112);  // row_shr:2
        DPP_MAX_STEP(m, 0x114);  // row_shr:4
        DPP_MAX_STEP(m, 0x118);  // row_shr:8
        DPP_MAX_STEP(m, 0x142);  // row_bcast:15
        DPP_MAX_STEP(m, 0x143);  // row_bcast:31
        // lane 63 now holds the max of all 64 lanes
        const float wavemax =
            __int_as_float(__builtin_amdgcn_readlane(__float_as_int(m), 63));

        // first-index tie-break: lowest set bit of the equality mask
        const unsigned long long eq = __ballot(acc == wavemax);
        const int idx = (int)__builtin_ctzll(eq);

        out[(size_t)r * 64u + lane] = (lane == idx) ? 1.0f : 0.0f;
    }
}

extern "C" void kernel_launch(void* const* d_in, const int* in_sizes, int n_in,
                              void* d_out, int out_size, void* d_ws, size_t ws_size,
                              hipStream_t stream) {
    const float* x = (const float*)d_in[0];
    const float* W = (const float*)d_in[1];
    const float* b = (const float*)d_in[2];
    float* out = (float*)d_out;

    const int nrows = in_sizes[0] / 64;

    dim3 block(256);
    dim3 grid(2048);  // 8192 waves -> 256 rows per wave at B=2M
    hipLaunchKernelGGL(onehot_argmax_kernel, grid, block, 0, stream,
                       x, W, b, out, nrows);
}

// Round 2
// 942.726 us; speedup vs baseline: 1.7323x; 1.7323x over previous
//
#include <hip/hip_runtime.h>

// Thread-per-row argmax-onehot.
//   - lane owns one row; x row streamed via vector float4 loads (VMEM path)
//   - W (16 KB, reused by every wave) read wave-uniformly -> s_load / scalar cache
//   - k-outer fmaf chain reproduces numpy/BLAS accumulation order exactly
//     (round-1 verified absmax == 0 with this ordering)
//   - output written as ONE perfectly-coalesced float4 stream per wave tile,
//     with the 1.0 embedded via __shfl of each row's argmax (no scatter, no RMW)

#define FMA4(A, XK, WR, J0)                      \
    (A).x = fmaf((XK), (WR)[(J0) + 0], (A).x);   \
    (A).y = fmaf((XK), (WR)[(J0) + 1], (A).y);   \
    (A).z = fmaf((XK), (WR)[(J0) + 2], (A).z);   \
    (A).w = fmaf((XK), (WR)[(J0) + 3], (A).w);

#define FMA64(XK, WR)                                                         \
    FMA4(a0, (XK), (WR), 0)   FMA4(a1, (XK), (WR), 4)                         \
    FMA4(a2, (XK), (WR), 8)   FMA4(a3, (XK), (WR), 12)                        \
    FMA4(a4, (XK), (WR), 16)  FMA4(a5, (XK), (WR), 20)                        \
    FMA4(a6, (XK), (WR), 24)  FMA4(a7, (XK), (WR), 28)                        \
    FMA4(a8, (XK), (WR), 32)  FMA4(a9, (XK), (WR), 36)                        \
    FMA4(a10, (XK), (WR), 40) FMA4(a11, (XK), (WR), 44)                       \
    FMA4(a12, (XK), (WR), 48) FMA4(a13, (XK), (WR), 52)                       \
    FMA4(a14, (XK), (WR), 56) FMA4(a15, (XK), (WR), 60)

#define ADDB(A, J0)                  \
    (A).x += bp[(J0) + 0];           \
    (A).y += bp[(J0) + 1];           \
    (A).z += bp[(J0) + 2];           \
    (A).w += bp[(J0) + 3];

#define CHK(V, J)                    \
    if ((V) > best) { best = (V); idx = (J); }

#define CHK4(A, J0)                  \
    CHK((A).x, (J0)) CHK((A).y, (J0) + 1) CHK((A).z, (J0) + 2) CHK((A).w, (J0) + 3)

__global__ __launch_bounds__(256) void onehot_argmax_kernel(
    const float* __restrict__ x, const float* __restrict__ W,
    const float* __restrict__ b, float* __restrict__ out, int nrows)
{
    const int lane = threadIdx.x & 63;
    const int wave = threadIdx.x >> 6;
    const long waveRow0 = (long)blockIdx.x * 256 + (long)wave * 64;
    const long r = waveRow0 + lane;

    const float4 z4 = make_float4(0.f, 0.f, 0.f, 0.f);
    float4 a0 = z4, a1 = z4, a2 = z4, a3 = z4, a4 = z4, a5 = z4, a6 = z4, a7 = z4;
    float4 a8 = z4, a9 = z4, a10 = z4, a11 = z4, a12 = z4, a13 = z4, a14 = z4, a15 = z4;

    if (r < nrows) {
        const float4* __restrict__ xr4 = (const float4*)(x + r * 64);
#pragma unroll 2
        for (int kk = 0; kk < 16; ++kk) {
            const float4 xv = xr4[kk];          // per-lane vector load (16 B/lane)
            const float* wr = W + kk * 256;     // wave-uniform -> scalar loads
            FMA64(xv.x, wr)
            FMA64(xv.y, wr + 64)
            FMA64(xv.z, wr + 128)
            FMA64(xv.w, wr + 192)
        }
    }

    // bias (single add per logit, matching reference) — wave-uniform scalar loads
    const float* __restrict__ bp = b;
    ADDB(a0, 0)  ADDB(a1, 4)  ADDB(a2, 8)   ADDB(a3, 12)
    ADDB(a4, 16) ADDB(a5, 20) ADDB(a6, 24)  ADDB(a7, 28)
    ADDB(a8, 32) ADDB(a9, 36) ADDB(a10, 40) ADDB(a11, 44)
    ADDB(a12, 48) ADDB(a13, 52) ADDB(a14, 56) ADDB(a15, 60)

    // first-index argmax (strict >) — matches numpy tie-break
    float best = a0.x;
    int idx = 0;
    CHK(a0.y, 1) CHK(a0.z, 2) CHK(a0.w, 3)
    CHK4(a1, 4)  CHK4(a2, 8)  CHK4(a3, 12) CHK4(a4, 16)
    CHK4(a5, 20) CHK4(a6, 24) CHK4(a7, 28) CHK4(a8, 32)
    CHK4(a9, 36) CHK4(a10, 40) CHK4(a11, 44) CHK4(a12, 48)
    CHK4(a13, 52) CHK4(a14, 56) CHK4(a15, 60)

    // Coalesced one-hot write: wave fills its 64-row tile (1024 float4s).
    // float4 #f of the tile belongs to row (f>>4), columns 4*(f&15)..+3.
    float4* __restrict__ outw = (float4*)(out + waveRow0 * 64);
    const long remf4 = ((long)nrows - waveRow0) * 16;  // float4s valid in tile
#pragma unroll
    for (int i = 0; i < 16; ++i) {
        const int f = i * 64 + lane;
        const int idx_r = __shfl(idx, f >> 4, 64);  // argmax of the row this f belongs to
        const bool m = ((idx_r >> 2) == (f & 15));
        const int c = idx_r & 3;
        float4 v;
        v.x = (m && c == 0) ? 1.0f : 0.0f;
        v.y = (m && c == 1) ? 1.0f : 0.0f;
        v.z = (m && c == 2) ? 1.0f : 0.0f;
        v.w = (m && c == 3) ? 1.0f : 0.0f;
        if (f < remf4) outw[f] = v;
    }
}

extern "C" void kernel_launch(void* const* d_in, const int* in_sizes, int n_in,
                              void* d_out, int out_size, void* d_ws, size_t ws_size,
                              hipStream_t stream) {
    const float* x = (const float*)d_in[0];
    const float* W = (const float*)d_in[1];
    const float* b = (const float*)d_in[2];
    float* out = (float*)d_out;

    const int nrows = in_sizes[0] / 64;
    dim3 block(256);
    dim3 grid((nrows + 255) / 256);  // 8192 blocks at B=2M
    hipLaunchKernelGGL(onehot_argmax_kernel, grid, block, 0, stream,
                       x, W, b, out, nrows);
}

// Round 3
// 934.813 us; speedup vs baseline: 1.7469x; 1.0085x over previous
//
#include <hip/hip_runtime.h>

// Thread-per-row argmax-onehot, v3.
//   - full x row hoisted into 16 named float4 VGPRs up-front (one load burst,
//     one wait) -> every 128-B line's touches are temporally adjacent -> no
//     HBM re-fetch (round-2 showed 45% x over-fetch from mid-loop eviction)
//   - W/b read wave-uniformly -> s_load / scalar cache (SGPR operand into FMA)
//   - k-ascending fmaf chain + single +b: bitwise-matches numpy ref (absmax 0
//     verified rounds 1-2)
//   - coalesced float4 one-hot tile store with __shfl'd argmax (round-2 code)

#define FMA4(A, XK, WR, J0)                      \
    (A).x = fmaf((XK), (WR)[(J0) + 0], (A).x);   \
    (A).y = fmaf((XK), (WR)[(J0) + 1], (A).y);   \
    (A).z = fmaf((XK), (WR)[(J0) + 2], (A).z);   \
    (A).w = fmaf((XK), (WR)[(J0) + 3], (A).w);

#define FMA64(XK, WR)                                                         \
    FMA4(a0, (XK), (WR), 0)   FMA4(a1, (XK), (WR), 4)                         \
    FMA4(a2, (XK), (WR), 8)   FMA4(a3, (XK), (WR), 12)                        \
    FMA4(a4, (XK), (WR), 16)  FMA4(a5, (XK), (WR), 20)                        \
    FMA4(a6, (XK), (WR), 24)  FMA4(a7, (XK), (WR), 28)                        \
    FMA4(a8, (XK), (WR), 32)  FMA4(a9, (XK), (WR), 36)                        \
    FMA4(a10, (XK), (WR), 40) FMA4(a11, (XK), (WR), 44)                       \
    FMA4(a12, (XK), (WR), 48) FMA4(a13, (XK), (WR), 52)                       \
    FMA4(a14, (XK), (WR), 56) FMA4(a15, (XK), (WR), 60)

// one x float4 (4 consecutive k) against W rows at base (W + KK*256)
#define FMABLK(XV, KK)                                                        \
    FMA64((XV).x, W + (KK) * 256)                                             \
    FMA64((XV).y, W + (KK) * 256 + 64)                                        \
    FMA64((XV).z, W + (KK) * 256 + 128)                                       \
    FMA64((XV).w, W + (KK) * 256 + 192)

#define ADDB(A, J0)                  \
    (A).x += bp[(J0) + 0];           \
    (A).y += bp[(J0) + 1];           \
    (A).z += bp[(J0) + 2];           \
    (A).w += bp[(J0) + 3];

#define CHK(V, J)                    \
    if ((V) > best) { best = (V); idx = (J); }

#define CHK4(A, J0)                  \
    CHK((A).x, (J0)) CHK((A).y, (J0) + 1) CHK((A).z, (J0) + 2) CHK((A).w, (J0) + 3)

__global__ __launch_bounds__(256) void onehot_argmax_kernel(
    const float* __restrict__ x, const float* __restrict__ W,
    const float* __restrict__ b, float* __restrict__ out, int nrows)
{
    const int lane = threadIdx.x & 63;
    const int wave = threadIdx.x >> 6;
    const long waveRow0 = (long)blockIdx.x * 256 + (long)wave * 64;
    const long r = waveRow0 + lane;

    const float4 z4 = make_float4(0.f, 0.f, 0.f, 0.f);
    float4 a0 = z4, a1 = z4, a2 = z4, a3 = z4, a4 = z4, a5 = z4, a6 = z4, a7 = z4;
    float4 a8 = z4, a9 = z4, a10 = z4, a11 = z4, a12 = z4, a13 = z4, a14 = z4, a15 = z4;

    if (r < nrows) {
        const float4* __restrict__ xr4 = (const float4*)(x + r * 64);
        // hoist the whole row: 16 back-to-back dwordx4 loads, one wait.
        const float4 x0 = xr4[0],  x1 = xr4[1],  x2 = xr4[2],  x3 = xr4[3];
        const float4 x4 = xr4[4],  x5 = xr4[5],  x6 = xr4[6],  x7 = xr4[7];
        const float4 x8 = xr4[8],  x9 = xr4[9],  x10 = xr4[10], x11 = xr4[11];
        const float4 x12 = xr4[12], x13 = xr4[13], x14 = xr4[14], x15 = xr4[15];

        FMABLK(x0, 0)   FMABLK(x1, 1)   FMABLK(x2, 2)   FMABLK(x3, 3)
        FMABLK(x4, 4)   FMABLK(x5, 5)   FMABLK(x6, 6)   FMABLK(x7, 7)
        FMABLK(x8, 8)   FMABLK(x9, 9)   FMABLK(x10, 10) FMABLK(x11, 11)
        FMABLK(x12, 12) FMABLK(x13, 13) FMABLK(x14, 14) FMABLK(x15, 15)
    }

    // bias (single add per logit, matching reference) — wave-uniform scalar loads
    const float* __restrict__ bp = b;
    ADDB(a0, 0)  ADDB(a1, 4)  ADDB(a2, 8)   ADDB(a3, 12)
    ADDB(a4, 16) ADDB(a5, 20) ADDB(a6, 24)  ADDB(a7, 28)
    ADDB(a8, 32) ADDB(a9, 36) ADDB(a10, 40) ADDB(a11, 44)
    ADDB(a12, 48) ADDB(a13, 52) ADDB(a14, 56) ADDB(a15, 60)

    // first-index argmax (strict >) — matches numpy tie-break
    float best = a0.x;
    int idx = 0;
    CHK(a0.y, 1) CHK(a0.z, 2) CHK(a0.w, 3)
    CHK4(a1, 4)  CHK4(a2, 8)  CHK4(a3, 12) CHK4(a4, 16)
    CHK4(a5, 20) CHK4(a6, 24) CHK4(a7, 28) CHK4(a8, 32)
    CHK4(a9, 36) CHK4(a10, 40) CHK4(a11, 44) CHK4(a12, 48)
    CHK4(a13, 52) CHK4(a14, 56) CHK4(a15, 60)

    // Coalesced one-hot write: wave fills its 64-row tile (1024 float4s).
    // float4 #f of the tile belongs to row (f>>4), columns 4*(f&15)..+3.
    float4* __restrict__ outw = (float4*)(out + waveRow0 * 64);
    const long remf4 = ((long)nrows - waveRow0) * 16;  // float4s valid in tile
#pragma unroll
    for (int i = 0; i < 16; ++i) {
        const int f = i * 64 + lane;
        const int idx_r = __shfl(idx, f >> 4, 64);  // argmax of the row this f belongs to
        const bool m = ((idx_r >> 2) == (f & 15));
        const int c = idx_r & 3;
        float4 v;
        v.x = (m && c == 0) ? 1.0f : 0.0f;
        v.y = (m && c == 1) ? 1.0f : 0.0f;
        v.z = (m && c == 2) ? 1.0f : 0.0f;
        v.w = (m && c == 3) ? 1.0f : 0.0f;
        if (f < remf4) outw[f] = v;
    }
}

extern "C" void kernel_launch(void* const* d_in, const int* in_sizes, int n_in,
                              void* d_out, int out_size, void* d_ws, size_t ws_size,
                              hipStream_t stream) {
    const float* x = (const float*)d_in[0];
    const float* W = (const float*)d_in[1];
    const float* b = (const float*)d_in[2];
    float* out = (float*)d_out;

    const int nrows = in_sizes[0] / 64;
    dim3 block(256);
    dim3 grid((nrows + 255) / 256);  // 8192 blocks at B=2M
    hipLaunchKernelGGL(onehot_argmax_kernel, grid, block, 0, stream,
                       x, W, b, out, nrows);
}